// Round 3
// baseline (210.319 us; speedup 1.0000x reference)
//
#include <hip/hip_runtime.h>

#define CLIP 4096
#define H1   2048
#define H2   1024
#define RN   4096
#define H_STEP 2.44140625f   // r_i = H_STEP*(i+1) exactly
#define G1   32768           // Sturm grid points per l

// ---- monotone float<->uint map for atomic min/max of floats -----------------
__device__ __forceinline__ unsigned fmap(float f) {
    unsigned u = __float_as_uint(f);
    return (u & 0x80000000u) ? ~u : (u | 0x80000000u);
}
__device__ __forceinline__ float funmap(unsigned u) {
    return __uint_as_float((u & 0x80000000u) ? (u & 0x7fffffffu) : ~u);
}
__device__ __forceinline__ void spect_bounds(const unsigned* bu, float& lo, float& cell) {
    float mn = funmap(bu[0]), mx = funmap(bu[1]);
    lo = mn - 1e-3f;                              // Gershgorin: lambda_min >= min ptl
    float hi = mx + 2.33554432f + 1e-3f;          // lambda_max <= max ptl + 2 + 2/r0^2
    cell = (hi - lo) * (1.0f / (float)G1);
}

// ---------------- GEMV: y[j] = sum_i x[i]*W[i,j]  (split-K partials) ---------
__global__ void gemv_part(const float* __restrict__ W, const float* __restrict__ x,
                          float* __restrict__ part, int N, int chunk,
                          unsigned* __restrict__ bu_init) {
    if (bu_init && blockIdx.x == 0 && blockIdx.y == 0 && threadIdx.x == 0) {
        bu_init[0] = 0xFFFFFFFFu;   // running min (mapped)
        bu_init[1] = 0u;            // running max (mapped)
    }
    int j = (blockIdx.x * blockDim.x + threadIdx.x) << 2;
    int i0 = blockIdx.y * chunk;
    float4 acc = make_float4(0.f, 0.f, 0.f, 0.f);
    const float* Wp = W + (size_t)i0 * N + j;
    for (int i = 0; i < chunk; ++i) {
        float xi = x[i0 + i];
        float4 w = *reinterpret_cast<const float4*>(Wp);
        acc.x = fmaf(xi, w.x, acc.x);
        acc.y = fmaf(xi, w.y, acc.y);
        acc.z = fmaf(xi, w.z, acc.z);
        acc.w = fmaf(xi, w.w, acc.w);
        Wp += N;
    }
    *reinterpret_cast<float4*>(part + (size_t)blockIdx.y * N + j) = acc;
}

__global__ void gemv_fin(const float* __restrict__ part, const float* __restrict__ b,
                         float* __restrict__ y, int N, int nch) {
    int j = blockIdx.x * 256 + threadIdx.x;
    float s = b[j];
    for (int c = 0; c < nch; ++c) s += part[(size_t)c * N + j];
    y[j] = fmaxf(s, 0.f);
}

// Last layer fin: write ptl (no relu), build D0/D1 = 2*diag (f64), atomic bounds.
__global__ void gemv_fin3(const float* __restrict__ part, const float* __restrict__ b,
                          float* __restrict__ out, double* __restrict__ D0,
                          double* __restrict__ D1, unsigned* __restrict__ bu, int nch) {
    __shared__ float smn[4], smx[4];
    int j = blockIdx.x * 256 + threadIdx.x;
    float s = b[j];
    for (int c = 0; c < nch; ++c) s += part[(size_t)c * RN + j];
    out[j] = s;                                   // ptl -> d_out[0:RN]
    float r = H_STEP * (float)(j + 1);
    double base = 2.0 * (1.0 + (double)s);
    D0[j] = base;
    D1[j] = base + (double)(4.0f / (r * r));
    // block min/max -> one atomic pair per block
    float mn = s, mx = s;
    for (int off = 32; off; off >>= 1) {
        mn = fminf(mn, __shfl_down(mn, off));
        mx = fmaxf(mx, __shfl_down(mx, off));
    }
    int tid = threadIdx.x;
    if ((tid & 63) == 0) { smn[tid >> 6] = mn; smx[tid >> 6] = mx; }
    __syncthreads();
    if (tid == 0) {
        for (int w = 1; w < 4; ++w) { mn = fminf(mn, smn[w]); mx = fmaxf(mx, smx[w]); }
        atomicMin(&bu[0], fmap(mn));
        atomicMax(&bu[1], fmap(mx));
    }
}

// -------- Sturm count via f64 char-poly recurrence  q_i = (D_i - X) q_{i-1} - q_{i-2}
// (D = 2*diag, X = 2*x; scaling kills the 0.25 coefficient -> one f64 fma/step.
//  f64 precision removes the sign-noise that made f32 counts non-monotone.)
__global__ __launch_bounds__(256) void stage1(const double* __restrict__ D0,
                                              const double* __restrict__ D1,
                                              const unsigned* __restrict__ bu,
                                              int* __restrict__ counts) {
    __shared__ alignas(16) double ds[RN];
    const double* Dsrc = blockIdx.y ? D1 : D0;
    for (int i = threadIdx.x; i < RN / 2; i += 256)
        reinterpret_cast<double2*>(ds)[i] = reinterpret_cast<const double2*>(Dsrc)[i];
    __syncthreads();

    float lo, cell;
    spect_bounds(bu, lo, cell);
    int j = blockIdx.x * 256 + threadIdx.x;
    double X = 2.0 * ((double)lo + (double)cell * (double)j);

    double pm1 = 1.0, pm2 = 0.0;
    unsigned cnt = 0;
    const double2* d2 = reinterpret_cast<const double2*>(ds);
    for (int blk = 0; blk < RN / 64; ++blk) {
#pragma unroll
        for (int u = 0; u < 32; ++u) {
            double2 dd = d2[blk * 32 + u];
            double p = fma(dd.x - X, pm1, -pm2);
            cnt += (unsigned)(__double2hiint(p) ^ __double2hiint(pm1)) >> 31;
            pm2 = pm1; pm1 = p;
            p = fma(dd.y - X, pm1, -pm2);
            cnt += (unsigned)(__double2hiint(p) ^ __double2hiint(pm1)) >> 31;
            pm2 = pm1; pm1 = p;
        }
        // renormalize max(|pm1|,|pm2|) exponent to ~0 (det=1 transfer matrix ->
        // 64-step growth/decay bounded by 2^~350, well inside f64 with rescale)
        unsigned a1 = (unsigned)__double2hiint(pm1) & 0x7fffffffu;
        unsigned a2 = (unsigned)__double2hiint(pm2) & 0x7fffffffu;
        unsigned hm = a1 > a2 ? a1 : a2;
        int es = 2046 - (int)(hm >> 20);
        es = es < 1 ? 1 : (es > 2045 ? 2045 : es);
        double sc = __hiloint2double(es << 20, 0);
        pm1 *= sc; pm2 *= sc;
    }
    counts[blockIdx.y * G1 + j] = (int)cnt;
}

// ------------- final: bracket search (noise-tolerant) + midpoint -------------
__global__ void final_eig(const int* __restrict__ counts, const unsigned* __restrict__ bu,
                          float* __restrict__ out) {
    int e = blockIdx.x * 256 + threadIdx.x;       // 8192 eigenvalues (l,k)
    int l = e >> 12, k = e & (RN - 1);
    const int* c = counts + l * G1;
    int lo_i = 0, hi_i = G1 - 1;                  // last j with c[j] <= k
    while (lo_i < hi_i) {
        int mid = (lo_i + hi_i + 1) >> 1;
        if (c[mid] <= k) lo_i = mid; else hi_i = mid - 1;
    }
    while (lo_i > 0 && c[lo_i] > k) --lo_i;       // local fixups (robustness)
    while (lo_i < G1 - 1 && c[lo_i + 1] <= k) ++lo_i;
    float lo, cell;
    spect_bounds(bu, lo, cell);
    out[e] = lo + cell * ((float)lo_i + 0.5f);
}

extern "C" void kernel_launch(void* const* d_in, const int* in_sizes, int n_in,
                              void* d_out, int out_size, void* d_ws, size_t ws_size,
                              hipStream_t stream) {
    const float* energy = (const float*)d_in[0];
    const float* W1 = (const float*)d_in[1];
    const float* b1 = (const float*)d_in[2];
    const float* W2 = (const float*)d_in[3];
    const float* b2 = (const float*)d_in[4];
    const float* W3 = (const float*)d_in[5];
    const float* b3 = (const float*)d_in[6];
    float* out = (float*)d_out;                   // [RN] ptl, then [2*RN] eigenvalues

    float* ws = (float*)d_ws;
    float*    part   = ws;                        // 262144 f32 (split-K partials, max 1 MB)
    float*    h1     = ws + 262144;               // 2048
    float*    h2     = h1 + H1;                   // 1024
    double*   D0     = (double*)(h2 + H2);        // 4096 f64 (16B-aligned offset)
    double*   D1     = D0 + RN;                   // 4096 f64
    unsigned* bu     = (unsigned*)(D1 + RN);      // 2 u32
    int*      counts = (int*)(bu + 4);            // 2*G1 i32

    // ---- MLP: 3 GEMVs, split-K tuned for >=128 blocks each ----
    gemv_part<<<dim3(2, 128), 256, 0, stream>>>(W1, energy, part, H1, CLIP / 128, bu);
    gemv_fin<<<H1 / 256, 256, 0, stream>>>(part, b1, h1, H1, 128);

    gemv_part<<<dim3(1, 128), 256, 0, stream>>>(W2, h1, part, H2, H1 / 128, nullptr);
    gemv_fin<<<H2 / 256, 256, 0, stream>>>(part, b2, h2, H2, 128);

    gemv_part<<<dim3(4, 64), 256, 0, stream>>>(W3, h2, part, RN, H2 / 64, nullptr);
    gemv_fin3<<<RN / 256, 256, 0, stream>>>(part, b3, out, D0, D1, bu, 64);

    // ---- Eigenvalues: single-stage f64 Sturm multisection ----
    stage1<<<dim3(G1 / 256, 2), 256, 0, stream>>>(D0, D1, bu, counts);
    final_eig<<<2 * RN / 256, 256, 0, stream>>>(counts, bu, out + RN);
}

// Round 4
// 98.283 us; speedup vs baseline: 2.1399x; 2.1399x over previous
//
#include <hip/hip_runtime.h>

#define CLIP 4096
#define H1   2048
#define H2   1024
#define RN   4096
#define H_STEP 2.44140625f   // r_i = H_STEP*(i+1) exactly
#define G1   32768           // Sturm grid points per l

// ---- monotone float<->uint map for atomic min/max of floats -----------------
__device__ __forceinline__ unsigned fmap(float f) {
    unsigned u = __float_as_uint(f);
    return (u & 0x80000000u) ? ~u : (u | 0x80000000u);
}
__device__ __forceinline__ float funmap(unsigned u) {
    return __uint_as_float((u & 0x80000000u) ? (u & 0x7fffffffu) : ~u);
}
__device__ __forceinline__ void spect_bounds(const unsigned* bu, float& lo, float& cell) {
    float mn = funmap(bu[0]), mx = funmap(bu[1]);
    lo = mn - 1e-3f;                              // Gershgorin: lambda_min >= min ptl
    float hi = mx + 2.33554432f + 1e-3f;          // lambda_max <= max ptl + 2 + 2/r0^2
    cell = (hi - lo) * (1.0f / (float)G1);
}

// ---------------- GEMV split-K: part[by][j] = sum_{i in chunk} x[i] W[i,j] ---
// One output column per thread (scalar) so j-blocks * k-blocks = 512 blocks
// (2048 waves in flight -> enough MLP memory parallelism to saturate HBM).
__global__ __launch_bounds__(256) void gemv_part(const float* __restrict__ W,
                                                 const float* __restrict__ x,
                                                 float* __restrict__ part, int N, int chunk,
                                                 unsigned* __restrict__ bu_init) {
    if (bu_init && blockIdx.x == 0 && blockIdx.y == 0 && threadIdx.x == 0) {
        bu_init[0] = 0xFFFFFFFFu;   // running min (mapped)
        bu_init[1] = 0u;            // running max (mapped)
    }
    int j = blockIdx.x * 256 + threadIdx.x;
    int i0 = blockIdx.y * chunk;
    const float* Wp = W + (size_t)i0 * N + j;
    float acc = 0.f;
#pragma unroll 8
    for (int i = 0; i < chunk; ++i)
        acc = fmaf(x[i0 + i], Wp[(size_t)i * N], acc);   // x: uniform -> s_load
    part[(size_t)blockIdx.y * N + j] = acc;
}

__global__ __launch_bounds__(256) void gemv_fin(const float* __restrict__ part,
                                                const float* __restrict__ b,
                                                float* __restrict__ y, int N, int nch) {
    int j = blockIdx.x * 256 + threadIdx.x;
    float s = b[j];
#pragma unroll 8
    for (int c = 0; c < nch; ++c) s += part[(size_t)c * N + j];
    y[j] = fmaxf(s, 0.f);
}

// Last-layer fin: ptl (no relu), D0/D1 = 2*diag (f32), atomic spectral bounds.
__global__ __launch_bounds__(256) void gemv_fin3(const float* __restrict__ part,
                                                 const float* __restrict__ b,
                                                 float* __restrict__ out,
                                                 float* __restrict__ D0, float* __restrict__ D1,
                                                 unsigned* __restrict__ bu, int nch) {
    __shared__ float smn[4], smx[4];
    int j = blockIdx.x * 256 + threadIdx.x;
    float s = b[j];
#pragma unroll 8
    for (int c = 0; c < nch; ++c) s += part[(size_t)c * RN + j];
    out[j] = s;                                   // ptl -> d_out[0:RN]
    float r = H_STEP * (float)(j + 1);
    float base = 2.0f + 2.0f * s;                 // 2*(1 + ptl)
    D0[j] = base;
    D1[j] = base + 4.0f / (r * r);                // + 2*l(l+1)/r^2, l=1
    float mn = s, mx = s;
    for (int off = 32; off; off >>= 1) {
        mn = fminf(mn, __shfl_down(mn, off));
        mx = fmaxf(mx, __shfl_down(mx, off));
    }
    int tid = threadIdx.x;
    if ((tid & 63) == 0) { smn[tid >> 6] = mn; smx[tid >> 6] = mx; }
    __syncthreads();
    if (tid == 0) {
        for (int w = 1; w < 4; ++w) { mn = fminf(mn, smn[w]); mx = fmaxf(mx, smx[w]); }
        atomicMin(&bu[0], fmap(mn));
        atomicMax(&bu[1], fmap(mx));
    }
}

// -------- Sturm count, f32 char-poly recurrence  q_i = (D_i - X) q_{i-1} - q_{i-2}
// D = 2*diag, X = 2*x kills the 0.25 coefficient -> exactly one fma per step
// (neg on q_{i-2} is a free input modifier). Sign changes = eigenvalue count.
#define STEP(dv)                                                           \
    {                                                                      \
        float t = (dv) - X;                                                \
        float p = fmaf(t, pm1, -pm2);                                      \
        cnt += (__float_as_uint(p) ^ __float_as_uint(pm1)) >> 31;          \
        pm2 = pm1; pm1 = p;                                                \
    }

__global__ __launch_bounds__(256) void stage1(const float* __restrict__ Dg0,
                                              const float* __restrict__ Dg1,
                                              const unsigned* __restrict__ bu,
                                              int* __restrict__ counts) {
    __shared__ alignas(16) float ds[RN];
    const float* Dsrc = blockIdx.y ? Dg1 : Dg0;
    for (int i = threadIdx.x; i < RN / 4; i += 256)
        reinterpret_cast<float4*>(ds)[i] = reinterpret_cast<const float4*>(Dsrc)[i];
    __syncthreads();

    float lo, cell;
    spect_bounds(bu, lo, cell);
    int j = blockIdx.x * 256 + threadIdx.x;
    float X = 2.0f * (lo + cell * (float)j);

    float pm1 = 1.0f, pm2 = 0.0f;
    unsigned cnt = 0;
    const float4* d4 = reinterpret_cast<const float4*>(ds);
    for (int w = 0; w < RN / 16; ++w) {
#pragma unroll
        for (int u = 0; u < 4; ++u) {
            float4 dd = d4[w * 4 + u];
            STEP(dd.x) STEP(dd.y) STEP(dd.z) STEP(dd.w)
        }
        // renormalize: bring max(|pm1|,|pm2|) exponent back to ~2^0.
        // growth/decay over 16 steps <= ~2^49 either way -> no over/underflow.
        unsigned a1 = __float_as_uint(pm1) & 0x7fffffffu;
        unsigned a2 = __float_as_uint(pm2) & 0x7fffffffu;
        unsigned hm = a1 > a2 ? a1 : a2;
        int es = 254 - (int)(hm >> 23);
        es = es < 67 ? 67 : (es > 187 ? 187 : es);   // clamp scale to 2^+-60
        float s = __uint_as_float((unsigned)es << 23);
        pm1 *= s; pm2 *= s;
    }
    counts[blockIdx.y * G1 + j] = (int)cnt;
}

// ------------- final: bracket search (noise-tolerant) + midpoint -------------
__global__ __launch_bounds__(256) void final_eig(const int* __restrict__ counts,
                                                 const unsigned* __restrict__ bu,
                                                 float* __restrict__ out) {
    int e = blockIdx.x * 256 + threadIdx.x;       // 8192 eigenvalues (l,k)
    int l = e >> 12, k = e & (RN - 1);
    const int* c = counts + l * G1;
    int lo_i = 0, hi_i = G1 - 1;                  // last j with c[j] <= k
    while (lo_i < hi_i) {
        int mid = (lo_i + hi_i + 1) >> 1;
        if (c[mid] <= k) lo_i = mid; else hi_i = mid - 1;
    }
    while (lo_i > 0 && c[lo_i] > k) --lo_i;       // +-1 noise fixups
    while (lo_i < G1 - 1 && c[lo_i + 1] <= k) ++lo_i;
    float lo, cell;
    spect_bounds(bu, lo, cell);
    out[e] = lo + cell * ((float)lo_i + 0.5f);
}

extern "C" void kernel_launch(void* const* d_in, const int* in_sizes, int n_in,
                              void* d_out, int out_size, void* d_ws, size_t ws_size,
                              hipStream_t stream) {
    const float* energy = (const float*)d_in[0];
    const float* W1 = (const float*)d_in[1];
    const float* b1 = (const float*)d_in[2];
    const float* W2 = (const float*)d_in[3];
    const float* b2 = (const float*)d_in[4];
    const float* W3 = (const float*)d_in[5];
    const float* b3 = (const float*)d_in[6];
    float* out = (float*)d_out;                   // [RN] ptl, then [2*RN] eigenvalues

    float* ws = (float*)d_ws;
    float*    part   = ws;                        // 131072 f32 (512 KB, reused per layer)
    float*    h1     = ws + 131072;               // 2048
    float*    h2     = h1 + H1;                   // 1024
    float*    D0     = h2 + H2;                   // 4096 (16B-aligned)
    float*    D1     = D0 + RN;                   // 4096
    unsigned* bu     = (unsigned*)(D1 + RN);      // 2 u32
    int*      counts = (int*)(bu + 4);            // 2*G1 i32

    // ---- MLP: 3 GEMVs, 512 blocks each (2048 waves -> HBM-saturating) ----
    gemv_part<<<dim3(8, 64), 256, 0, stream>>>(W1, energy, part, H1, CLIP / 64, bu);
    gemv_fin<<<H1 / 256, 256, 0, stream>>>(part, b1, h1, H1, 64);

    gemv_part<<<dim3(4, 128), 256, 0, stream>>>(W2, h1, part, H2, H1 / 128, nullptr);
    gemv_fin<<<H2 / 256, 256, 0, stream>>>(part, b2, h2, H2, 128);

    gemv_part<<<dim3(16, 32), 256, 0, stream>>>(W3, h2, part, RN, H2 / 32, nullptr);
    gemv_fin3<<<RN / 256, 256, 0, stream>>>(part, b3, out, D0, D1, bu, 32);

    // ---- Eigenvalues: single-stage f32 Sturm multisection ----
    stage1<<<dim3(G1 / 256, 2), 256, 0, stream>>>(D0, D1, bu, counts);
    final_eig<<<2 * RN / 256, 256, 0, stream>>>(counts, bu, out + RN);
}